// Round 13
// baseline (50.398 us; speedup 1.0000x reference)
//
#include <hip/hip_runtime.h>
#include <hip/hip_bf16.h>

#define DD 128
#define NEGS 0.01f

typedef float  f32x4 __attribute__((ext_vector_type(4)));
typedef __bf16 bf16x8 __attribute__((ext_vector_type(8)));
typedef unsigned short us8 __attribute__((ext_vector_type(8)));

__device__ __forceinline__ unsigned short f2bf(float f) {
    unsigned int u = __builtin_bit_cast(unsigned int, f);
    u += 0x7FFFu + ((u >> 16) & 1u);          // RNE (no NaN inputs here)
    return (unsigned short)(u >> 16);
}
__device__ __forceinline__ float sb2f(unsigned int u, int byte) {
    return (float)(int)(signed char)((u >> (byte * 8)) & 0xffu);
}

// ---------- fused GEMM + logits + row-quant + segment-starts ---------------
// (identical to round 10 — best known)
__global__ __launch_bounds__(256)
void k_gemm(const float* __restrict__ h, const float* __restrict__ W,
            const float* __restrict__ attn, const int* __restrict__ dst,
            int E, int N, int NB,
            signed char* __restrict__ z8, float2* __restrict__ lls,
            float* __restrict__ lrv, int* __restrict__ start)
{
    if (blockIdx.x >= NB) {               // ---- segment starts part ----
        int n = (blockIdx.x - NB) * 256 + threadIdx.x;
        if (n > N) return;
        int lo = 0, hi = E;
        while (lo < hi) {
            int mid = (lo + hi) >> 1;
            if (dst[mid] < n) lo = mid + 1; else hi = mid;
        }
        start[n] = lo;
        return;
    }

    __shared__ unsigned short hs[128 * DD];   // 32 KB, swizzled bf16
    __shared__ unsigned short ws[DD * DD];    // 32 KB, swizzled bf16
    const int tid  = threadIdx.x;
    const int row0 = blockIdx.x * 128;

    {   // stage W (fp32 -> bf16, swizzled)
        const int r = tid >> 4, c = tid & 15;
#pragma unroll
        for (int p = 0; p < DD; p += 16) {
            const int rr = p + r;
            const float* pw = W + (size_t)rr * DD + c * 8;
            float4 a = *(const float4*)pw, b = *(const float4*)(pw + 4);
            us8 v = { f2bf(a.x), f2bf(a.y), f2bf(a.z), f2bf(a.w),
                      f2bf(b.x), f2bf(b.y), f2bf(b.z), f2bf(b.w) };
            *(us8*)(ws + rr * DD + ((c ^ (rr & 15)) * 8)) = v;
        }
    }
    {   // stage h rows [row0, row0+128) (clamped)
        const int r = tid >> 4, c = tid & 15;
#pragma unroll
        for (int p = 0; p < 128; p += 16) {
            const int rr = p + r;
            int gr = row0 + rr; if (gr > N - 1) gr = N - 1;
            const float* ph = h + (size_t)gr * DD + c * 8;
            float4 a = *(const float4*)ph, b = *(const float4*)(ph + 4);
            us8 v = { f2bf(a.x), f2bf(a.y), f2bf(a.z), f2bf(a.w),
                      f2bf(b.x), f2bf(b.y), f2bf(b.z), f2bf(b.w) };
            *(us8*)(hs + rr * DD + ((c ^ (rr & 15)) * 8)) = v;
        }
    }
    __syncthreads();

    const int w    = tid >> 6;
    const int lane = tid & 63;
    const int hl   = lane & 15;
    const int g    = lane >> 4;

    f32x4 acc[2][8];
#pragma unroll
    for (int rt = 0; rt < 2; ++rt)
#pragma unroll
        for (int jt = 0; jt < 8; ++jt) acc[rt][jt] = f32x4{0.f, 0.f, 0.f, 0.f};

#pragma unroll
    for (int kk = 0; kk < DD; kk += 32) {
        const int cb = (kk >> 3) + g;
        const int ra0 = w * 32 + hl;
        const int ra1 = ra0 + 16;
        bf16x8 a0 = *(const bf16x8*)(hs + ra0 * DD + ((cb ^ (ra0 & 15)) * 8));
        bf16x8 a1 = *(const bf16x8*)(hs + ra1 * DD + ((cb ^ (ra1 & 15)) * 8));
#pragma unroll
        for (int jt = 0; jt < 8; ++jt) {
            const int rb = jt * 16 + hl;
            bf16x8 b = *(const bf16x8*)(ws + rb * DD + ((cb ^ (rb & 15)) * 8));
            acc[0][jt] = __builtin_amdgcn_mfma_f32_16x16x32_bf16(a0, b, acc[0][jt], 0, 0, 0);
            acc[1][jt] = __builtin_amdgcn_mfma_f32_16x16x32_bf16(a1, b, acc[1][jt], 0, 0, 0);
        }
    }

    // epilogue: logits + row absmax + int8 quantize
    float aLc[8], aRc[8];
#pragma unroll
    for (int jt = 0; jt < 8; ++jt) {
        aLc[jt] = attn[jt * 16 + hl];
        aRc[jt] = attn[DD + jt * 16 + hl];
    }
#pragma unroll
    for (int rt = 0; rt < 2; ++rt) {
#pragma unroll
        for (int reg = 0; reg < 4; ++reg) {
            const int row = row0 + w * 32 + rt * 16 + g * 4 + reg;
            float pl = 0.f, pr = 0.f, am = 0.f;
#pragma unroll
            for (int jt = 0; jt < 8; ++jt) {
                float v = acc[rt][jt][reg];
                pl = fmaf(v, aLc[jt], pl);
                pr = fmaf(v, aRc[jt], pr);
                am = fmaxf(am, fabsf(v));
            }
#pragma unroll
            for (int o = 8; o >= 1; o >>= 1) {   // reduce across 16 cols
                pl += __shfl_xor(pl, o);
                pr += __shfl_xor(pr, o);
                am = fmaxf(am, __shfl_xor(am, o));
            }
            if (row < N) {
                const float inv_s = (am > 0.f) ? 127.f / am : 0.f;
                if (hl == 0) {
                    lls[row] = make_float2(pl, am * (1.f / 127.f));
                    lrv[row] = pr;
                }
                signed char* zr = z8 + (size_t)row * DD;
#pragma unroll
                for (int jt = 0; jt < 8; ++jt)
                    zr[jt * 16 + hl] =
                        (signed char)__float2int_rn(acc[rt][jt][reg] * inv_s);
            }
        }
    }
}

// ---------------- fused output: half-wave per node, 8 lanes per row --------
// 32 lanes own one node: 4 groups x 8 lanes; group g handles edge base+g,
// its 8 lanes read the full 128B z8 row (uint4, 16B/lane). Per wave-iter:
// 1 src + 1 lls + 1 z VMEM instr covering 8 edges (2 nodes). 4-edge loop
// granularity halves padding waste vs 8/16. Reductions xor8+xor16 stay
// within the half-wave; one full-wave 512B nt-store writes both rows.
// No max-subtraction (logits O(10), exp fp32-safe, softmax shift-invariant).
__global__ __launch_bounds__(256)
void k_out(const signed char* __restrict__ z8, const int* __restrict__ src,
           const float2* __restrict__ lls, const float* __restrict__ lrv,
           const int* __restrict__ start, float* __restrict__ out, int N)
{
    const int node  = (blockIdx.x * 256 + threadIdx.x) >> 5;   // half-wave id
    const int l32   = threadIdx.x & 31;
    if (node >= N) return;
    const int g = l32 >> 3;       // group 0..3: edge base+g
    const int k = l32 & 7;        // slice lane: bytes 16k .. 16k+15 of the row
    const int s0 = start[node], s1 = start[node + 1];
    const float lrn = lrv[node];
    const int last = s1 - 1;

    f32x4 acc0 = {0.f, 0.f, 0.f, 0.f};
    f32x4 acc1 = {0.f, 0.f, 0.f, 0.f};
    f32x4 acc2 = {0.f, 0.f, 0.f, 0.f};
    f32x4 acc3 = {0.f, 0.f, 0.f, 0.f};
    float ssum = 0.f;

    for (int base = s0; base < s1; base += 4) {
        int t  = base + g;
        int tc = (t <= last) ? t : last;
        int sj = __builtin_nontemporal_load(src + tc);   // broadcast in group
        float2 p = lls[sj];                              // broadcast in group
        float v = p.x + lrn;  v = (v >= 0.f) ? v : NEGS * v;
        float w = __expf(v); if (t > last) w = 0.f;
        uint4 z = *(const uint4*)(z8 + (size_t)sj * DD + k * 16);
        ssum += w;
        float u = w * p.y;
        acc0[0] = fmaf(u, sb2f(z.x, 0), acc0[0]);
        acc0[1] = fmaf(u, sb2f(z.x, 1), acc0[1]);
        acc0[2] = fmaf(u, sb2f(z.x, 2), acc0[2]);
        acc0[3] = fmaf(u, sb2f(z.x, 3), acc0[3]);
        acc1[0] = fmaf(u, sb2f(z.y, 0), acc1[0]);
        acc1[1] = fmaf(u, sb2f(z.y, 1), acc1[1]);
        acc1[2] = fmaf(u, sb2f(z.y, 2), acc1[2]);
        acc1[3] = fmaf(u, sb2f(z.y, 3), acc1[3]);
        acc2[0] = fmaf(u, sb2f(z.z, 0), acc2[0]);
        acc2[1] = fmaf(u, sb2f(z.z, 1), acc2[1]);
        acc2[2] = fmaf(u, sb2f(z.z, 2), acc2[2]);
        acc2[3] = fmaf(u, sb2f(z.z, 3), acc2[3]);
        acc3[0] = fmaf(u, sb2f(z.w, 0), acc3[0]);
        acc3[1] = fmaf(u, sb2f(z.w, 1), acc3[1]);
        acc3[2] = fmaf(u, sb2f(z.w, 2), acc3[2]);
        acc3[3] = fmaf(u, sb2f(z.w, 3), acc3[3]);
    }
    // reduce over the 4 groups (xor 8, xor 16 — stay within the half-wave)
#pragma unroll
    for (int o = 8; o <= 16; o <<= 1) {
#pragma unroll
        for (int i = 0; i < 4; ++i) {
            acc0[i] += __shfl_xor(acc0[i], o);
            acc1[i] += __shfl_xor(acc1[i], o);
            acc2[i] += __shfl_xor(acc2[i], o);
            acc3[i] += __shfl_xor(acc3[i], o);
        }
        ssum += __shfl_xor(ssum, o);
    }
    float inv = (s1 > s0) ? 1.0f / ssum : 0.f;   // empty segment -> zeros

    // lane (g,k) stores cols k*16 + g*4 .. +3 -> full 512B row per half-wave
    f32x4 sel = (g == 0) ? acc0 : (g == 1) ? acc1 : (g == 2) ? acc2 : acc3;
    f32x4 o = {sel[0] * inv, sel[1] * inv, sel[2] * inv, sel[3] * inv};
    __builtin_nontemporal_store(o,
        (f32x4*)(out + (size_t)node * DD + k * 16 + g * 4));
}

extern "C" void kernel_launch(void* const* d_in, const int* in_sizes, int n_in,
                              void* d_out, int out_size, void* d_ws, size_t ws_size,
                              hipStream_t stream) {
    const float* h    = (const float*)d_in[0];
    const int*   src  = (const int*)d_in[1];
    const int*   dst  = (const int*)d_in[2];
    const float* W    = (const float*)d_in[3];
    const float* attn = (const float*)d_in[4];
    const int N = in_sizes[0] / DD;
    const int E = in_sizes[1];
    float* out = (float*)d_out;

    // workspace layout (z8 6.4 MB, lls 400 KB, lrv 200 KB, start)
    signed char* z8 = (signed char*)d_ws;               // N*128 int8
    float2* lls = (float2*)(z8 + (size_t)N * DD);       // N float2 {ll, s}
    float* lrv  = (float*)(lls + N);                    // N
    int* start  = (int*)(lrv + N);                      // N+1

    const int NB = (N + 127) / 128;          // gemm blocks
    const int SB = (N + 1 + 255) / 256;      // starts blocks

    k_gemm<<<NB + SB, 256, 0, stream>>>(h, W, attn, dst, E, N, NB, z8, lls, lrv, start);
    k_out<<<(N + 7) / 8, 256, 0, stream>>>(z8, src, lls, lrv, start, out, N);
}